// Round 9
// baseline (661.284 us; speedup 1.0000x reference)
//
#include <hip/hip_runtime.h>
#include <math.h>

#define N_NODES 50000
#define N_EDGES 500000
#define D 128
#define H 256
#define NE 64
#define TOPK 2
#define NPAIR (N_NODES * TOPK)
#define CAP 3126               // 2 * ceil(100000/64)
#define TILE_R 32
#define BQ 16                  // blocks per expert in k_moe
#define BN_NBLK 128
#define BN_ROWS ((N_NODES + BN_NBLK - 1) / BN_NBLK) // 391

typedef __attribute__((ext_vector_type(8))) short s16x8;
typedef __attribute__((ext_vector_type(4))) float f32x4;

__device__ __forceinline__ unsigned short f2bf(float f) {
    unsigned u = __float_as_uint(f);
    unsigned r = (u + 0x7fffu + ((u >> 16) & 1u)) >> 16;
    return (unsigned short)r;
}
__device__ __forceinline__ float bf2f(unsigned short u) {
    return __uint_as_float(((unsigned)u) << 16);
}

// Compensated f32: TwoProd (mul + fma residual) + branch-free TwoSum.
#define DOT2(s, c, xx, ww) {                      \
    float p_ = (xx) * (ww);                       \
    float e1_ = fmaf((xx), (ww), -p_);            \
    float t_ = (s) + p_;                          \
    float z_ = t_ - (s);                          \
    float e2_ = ((s) - (t_ - z_)) + (p_ - z_);    \
    (s) = t_;                                     \
    (c) += e1_ + e2_; }

#define TSUM(s, c, pp) {                          \
    float p_ = (pp);                              \
    float t_ = (s) + p_;                          \
    float z_ = t_ - (s);                          \
    float e2_ = ((s) - (t_ - z_)) + (p_ - z_);    \
    (s) = t_;                                     \
    (c) += e2_; }

// ---------------- degree count ----------------
__global__ void k_deg(const int* __restrict__ dst, int* __restrict__ deg) {
    int i = blockIdx.x * blockDim.x + threadIdx.x;
    if (i < N_EDGES) atomicAdd(&deg[dst[i]], 1);
}

__global__ void k_invsqrt(const int* __restrict__ deg, float* __restrict__ invs) {
    int i = blockIdx.x * blockDim.x + threadIdx.x;
    if (i < N_NODES) {
        double d = (double)deg[i];
        if (d < 1.0) d = 1.0;
        invs[i] = (float)(1.0 / sqrt(d));
    }
}

// ---------------- exclusive scan of deg -> rowptr ----------------
__global__ __launch_bounds__(1024) void k_scan(const int* __restrict__ deg,
                                               int* __restrict__ rowptr) {
    __shared__ int sh[1024];
    int t = threadIdx.x;
    const int chunk = (N_NODES + 1023) / 1024;   // 49
    int lo = t * chunk;
    int hi = min(lo + chunk, N_NODES);
    int s = 0;
    for (int i = lo; i < hi; i++) s += deg[i];
    sh[t] = s;
    __syncthreads();
    for (int off = 1; off < 1024; off <<= 1) {
        int v = (t >= off) ? sh[t - off] : 0;
        __syncthreads();
        sh[t] += v;
        __syncthreads();
    }
    int run = (t == 0) ? 0 : sh[t - 1];
    for (int i = lo; i < hi; i++) { rowptr[i] = run; run += deg[i]; }
    if (t == 1023) rowptr[N_NODES] = run;
}

// ---------------- scatter edges into CSR ----------------
__global__ void k_scatter(const int* __restrict__ src, const int* __restrict__ dst,
                          const int* __restrict__ rowptr, int* __restrict__ cursor,
                          int* __restrict__ csr) {
    int e = blockIdx.x * blockDim.x + threadIdx.x;
    if (e >= N_EDGES) return;
    int d = dst[e];
    int pos = atomicAdd(&cursor[d], 1);
    csr[rowptr[d] + pos] = src[e];
}

// ---------------- per-node gather (compensated f32, order-independent ~1e-12) ----
__global__ __launch_bounds__(256) void k_gather(const float* __restrict__ feats,
                                                const int* __restrict__ rowptr,
                                                const int* __restrict__ csr,
                                                const float* __restrict__ invs,
                                                float* __restrict__ agg) {
    int node = blockIdx.x * 4 + (threadIdx.x >> 6);
    if (node >= N_NODES) return;
    int lane = threadIdx.x & 63;
    int beg = rowptr[node], end = rowptr[node + 1];
    float wd = invs[node];
    float sx = 0.f, cx = 0.f, sy = 0.f, cy = 0.f;
    for (int i = beg; i < end; i++) {
        int s = csr[i];
        float nrm = invs[s] * wd;
        float2 f = ((const float2*)(feats + (size_t)s * D))[lane];
        DOT2(sx, cx, nrm, f.x);
        DOT2(sy, cy, nrm, f.y);
    }
    ((float2*)(agg + (size_t)node * D))[lane] = make_float2(sx + cx, sy + cy);
}

// ---------------- conv GEMM: new_feats = agg @ W_conv + b_conv (fp32, untouched) ----
__global__ __launch_bounds__(256) void k_conv(const float* __restrict__ agg,
                                              const float* __restrict__ W,
                                              const float* __restrict__ bias,
                                              float* __restrict__ out) {
    __shared__ float Wl[D * D];        // 64 KB
    __shared__ float xl[TILE_R * D];   // 16 KB
    int r0 = blockIdx.x * TILE_R;
    int rows = min(TILE_R, N_NODES - r0);
    for (int i = threadIdx.x; i < D * D / 4; i += 256)
        ((float4*)Wl)[i] = ((const float4*)W)[i];
    for (int i = threadIdx.x; i < rows * 32; i += 256) {
        int r = i >> 5, q = i & 31;
        ((float4*)(xl + r * D))[q] = ((const float4*)(agg + (size_t)(r0 + r) * D))[q];
    }
    __syncthreads();
    int c = threadIdx.x & 127;
    int half = threadIdx.x >> 7;
    float acc[16];
#pragma unroll
    for (int j = 0; j < 16; j++) acc[j] = 0.f;
    for (int k = 0; k < D; k++) {
        float w = Wl[k * D + c];
#pragma unroll
        for (int j = 0; j < 16; j++) acc[j] += xl[(half + j * 2) * D + k] * w;
    }
    float b = bias[c];
#pragma unroll
    for (int j = 0; j < 16; j++) {
        int r = half + j * 2;
        if (r < rows) out[(size_t)(r0 + r) * D + c] = acc[j] + b;
    }
}

// ---------------- gate v5: comp-f32 scores, (v,r,idx) top-2, no atomics ----------------
__global__ __launch_bounds__(256) void k_gate(const float* __restrict__ nf,
                                              const float* __restrict__ gW,
                                              const float* __restrict__ gb,
                                              float* __restrict__ gwout,
                                              int* __restrict__ topi) {
    __shared__ float Wl[D * NE];       // 32 KB, layout [k][e]
    __shared__ float xsh[16 * D];      // 8 KB
    for (int i = threadIdx.x; i < D * NE / 4; i += 256)
        ((float4*)Wl)[i] = ((const float4*)gW)[i];
    int t_base = blockIdx.x * 16;
    for (int i = threadIdx.x; i < 16 * 32; i += 256) {
        int r = i >> 5, q = i & 31;
        ((float4*)(xsh + r * D))[q] =
            ((const float4*)(nf + (size_t)(t_base + r) * D))[q];
    }
    __syncthreads();

    int wave = threadIdx.x >> 6;
    int lane = threadIdx.x & 63;      // lane = expert
    int t0 = t_base + wave * 4;
    const float* xw = xsh + wave * 4 * D;

    float s0 = 0.f, c0 = 0.f, s1 = 0.f, c1 = 0.f;
    float s2 = 0.f, c2 = 0.f, s3 = 0.f, c3 = 0.f;
    for (int k4 = 0; k4 < D; k4 += 4) {
        float x0[4], x1[4], x2[4], x3[4];
        *(float4*)x0 = *(const float4*)(xw + k4);
        *(float4*)x1 = *(const float4*)(xw + D + k4);
        *(float4*)x2 = *(const float4*)(xw + 2 * D + k4);
        *(float4*)x3 = *(const float4*)(xw + 3 * D + k4);
#pragma unroll
        for (int u = 0; u < 4; u++) {
            float w = Wl[(k4 + u) * NE + lane];
            DOT2(s0, c0, x0[u], w);
            DOT2(s1, c1, x1[u], w);
            DOT2(s2, c2, x2[u], w);
            DOT2(s3, c3, x3[u], w);
        }
    }
    float gbf = gb[lane];
    TSUM(s0, c0, gbf);
    TSUM(s1, c1, gbf);
    TSUM(s2, c2, gbf);
    TSUM(s3, c3, gbf);
    float v0 = s0 + c0, r0 = (s0 - v0) + c0;
    float v1 = s1 + c1, r1 = (s1 - v1) + c1;
    float v2 = s2 + c2, r2 = (s2 - v2) + c2;
    float v3 = s3 + c3, r3 = (s3 - v3) + c3;

#pragma unroll
    for (int j = 0; j < 4; j++) {
        float vv = (j == 0) ? v0 : (j == 1) ? v1 : (j == 2) ? v2 : v3;
        float rr = (j == 0) ? r0 : (j == 1) ? r1 : (j == 2) ? r2 : r3;
        int t = t0 + j;

        float a1v = vv, a1r = rr; int i1 = lane;
#pragma unroll
        for (int off = 32; off; off >>= 1) {
            float ov = __shfl_xor(a1v, off);
            float orr = __shfl_xor(a1r, off);
            int   oi = __shfl_xor(i1, off);
            bool gt = (ov > a1v) || (ov == a1v && (orr > a1r || (orr == a1r && oi < i1)));
            if (gt) { a1v = ov; a1r = orr; i1 = oi; }
        }
        bool ex = (lane == i1);
        float a2v = ex ? -INFINITY : vv;
        float a2r = ex ? 0.f : rr;
        int i2 = lane;
#pragma unroll
        for (int off = 32; off; off >>= 1) {
            float ov = __shfl_xor(a2v, off);
            float orr = __shfl_xor(a2r, off);
            int   oi = __shfl_xor(i2, off);
            bool gt = (ov > a2v) || (ov == a2v && (orr > a2r || (orr == a2r && oi < i2)));
            if (gt) { a2v = ov; a2r = orr; i2 = oi; }
        }

        if (lane == 0) {
            float dd = (a2v - a1v) + (a2r - a1r);
            float e2 = expf(dd);
            float g0 = 1.0f / (1.0f + e2);
            gwout[2 * t] = g0;
            gwout[2 * t + 1] = e2 * g0;
            topi[2 * t] = i1;
            topi[2 * t + 1] = i2;
        }
    }
}

// ---------------- dispatch: parallel two-level counting scatter ----------------
__global__ __launch_bounds__(1024) void k_disp(const int* __restrict__ topi,
                                               int* __restrict__ cnt,
                                               int* __restrict__ plist) {
    __shared__ int lcnt[NE];
    __shared__ int lbase[NE];
    int tid = threadIdx.x;
    if (tid < NE) lcnt[tid] = 0;
    __syncthreads();
    int p = blockIdx.x * 1024 + tid;
    int e = 0, lr = 0;
    bool act = (p < NPAIR);
    if (act) {
        e = topi[p];
        lr = atomicAdd(&lcnt[e], 1);
    }
    __syncthreads();
    if (tid < NE) {
        int n = lcnt[tid];
        lbase[tid] = n ? atomicAdd(&cnt[tid], n) : 0;
    }
    __syncthreads();
    if (act) {
        int slot = lbase[e] + lr;
        if (slot < CAP) plist[e * CAP + slot] = p;
    }
}

// ---------------- weight convert: f32 -> bf16 in MFMA fragment layout --------------
// w1c: [e][ks=4][h=256][lhi=4][8 bf16]   (k = ks*32 + lhi*8 + j, i.e. W1^T fragments)
// w2c: [e][ks=8][d=128][lhi=4][8 bf16]   (k = ks*32 + lhi*8 + j, i.e. W2^T fragments)
__global__ __launch_bounds__(256) void k_wconv(const float* __restrict__ W1,
                                               const float* __restrict__ W2,
                                               unsigned short* __restrict__ w1c,
                                               unsigned short* __restrict__ w2c) {
    int gid = blockIdx.x * 256 + threadIdx.x;
    const int NW1 = NE * 4 * 256 * 4;            // 262144
    if (gid < NW1) {
        int lhi = gid & 3, h = (gid >> 2) & 255, ks = (gid >> 10) & 3, e = gid >> 12;
        int d0 = ks * 32 + lhi * 8;
        unsigned short v[8] __attribute__((aligned(16)));
#pragma unroll
        for (int j = 0; j < 8; j++)
            v[j] = f2bf(W1[((size_t)e * D + d0 + j) * H + h]);
        *(int4*)(w1c + (size_t)gid * 8) = *(int4*)v;
    } else {
        int g = gid - NW1;
        int lhi = g & 3, d = (g >> 2) & 127, ks = (g >> 9) & 7, e = g >> 12;
        int h0 = ks * 32 + lhi * 8;
        unsigned short v[8] __attribute__((aligned(16)));
#pragma unroll
        for (int j = 0; j < 8; j++)
            v[j] = f2bf(W2[((size_t)e * H + h0 + j) * D + d]);
        *(int4*)(w2c + (size_t)g * 8) = *(int4*)v;
    }
}

// ---------------- MoE FFN v3: bf16 MFMA, B-fragments streamed from L2 --------------
// LDS only: XA [32][128] bf16 (8 KB) + HL [32][256] bf16 (16 KB), XOR-swizzled.
__global__ __launch_bounds__(256, 4) void k_moe(const float* __restrict__ nf,
                                                const int* __restrict__ cnt,
                                                const int* __restrict__ plist,
                                                const unsigned short* __restrict__ w1c,
                                                const float* __restrict__ b1,
                                                const unsigned short* __restrict__ w2c,
                                                const float* __restrict__ b2,
                                                const float* __restrict__ gwbuf,
                                                unsigned short* __restrict__ ybuf) {
    __shared__ __align__(16) char smem[24576];
    const int XA = 0, HL = 8192;
    int e = blockIdx.x & 63;         // same-expert blocks land on same XCD
    int q = blockIdx.x >> 6;
    int n = min(cnt[e], CAP);
    int ntile = (n + TILE_R - 1) / TILE_R;
    int tid = threadIdx.x;
    int wv = tid >> 6, lane = tid & 63;
    int lhi = lane >> 4, llo = lane & 15;
    f32x4 zero = {0.f, 0.f, 0.f, 0.f};

    for (int rt = q; rt < ntile; rt += BQ) {
        int r0 = rt * TILE_R;
        int rows = min(TILE_R, n - r0);
        __syncthreads();   // XA/HL safe to overwrite

        // ---- gather 32 x-rows -> XA (bf16, swizzled) ----
        {
            int r = tid >> 3, s = tid & 7;
            float vals[16];
            if (r < rows) {
                int p = plist[e * CAP + r0 + r];
                const float4* xr = (const float4*)(nf + (size_t)(p >> 1) * D + s * 16);
                *(float4*)(vals + 0)  = xr[0];
                *(float4*)(vals + 4)  = xr[1];
                *(float4*)(vals + 8)  = xr[2];
                *(float4*)(vals + 12) = xr[3];
            } else {
#pragma unroll
                for (int k = 0; k < 16; k++) vals[k] = 0.f;
            }
            unsigned short hb[16] __attribute__((aligned(16)));
#pragma unroll
            for (int k = 0; k < 16; k++) hb[k] = f2bf(vals[k]);
            int colb = s * 32;
            *(int4*)(smem + XA + r * 256 + ((colb)      ^ ((r & 7) << 4))) = *(int4*)(hb);
            *(int4*)(smem + XA + r * 256 + ((colb + 16) ^ ((r & 7) << 4))) = *(int4*)(hb + 8);
        }
        __syncthreads();

        // ---- GEMM1: H[32x256] = X @ W1; wave wv owns h-cols [wv*64, +64) ----
        f32x4 acc1[2][4];
#pragma unroll
        for (int mt = 0; mt < 2; mt++)
#pragma unroll
            for (int nt = 0; nt < 4; nt++) acc1[mt][nt] = zero;
#pragma unroll
        for (int ks = 0; ks < 4; ks++) {
            int kb = ks * 64 + lhi * 16;
            s16x8 a0 = *(const s16x8*)(smem + XA + llo * 256        + (kb ^ ((llo & 7) << 4)));
            s16x8 a1 = *(const s16x8*)(smem + XA + (llo + 16) * 256 + (kb ^ ((llo & 7) << 4)));
#pragma unroll
            for (int nt = 0; nt < 4; nt++) {
                int h = wv * 64 + nt * 16 + llo;
                s16x8 b = *(const s16x8*)((const char*)w1c +
                          ((((size_t)(e * 4 + ks) << 8) + h) * 4 + lhi) * 16);
                acc1[0][nt] = __builtin_amdgcn_mfma_f32_16x16x32_bf16(a0, b, acc1[0][nt], 0, 0, 0);
                acc1[1][nt] = __builtin_amdgcn_mfma_f32_16x16x32_bf16(a1, b, acc1[1][nt], 0, 0, 0);
            }
        }

        // ---- gelu -> HL (bf16, swizzled) ----
#pragma unroll
        for (int mt = 0; mt < 2; mt++)
#pragma unroll
            for (int nt = 0; nt < 4; nt++)
#pragma unroll
                for (int r = 0; r < 4; r++) {
                    int m = mt * 16 + lhi * 4 + r;
                    int hc = wv * 64 + nt * 16 + llo;
                    float hv = acc1[mt][nt][r] + b1[e * H + hc];
                    float g = 0.5f * hv * (1.0f + erff(hv * 0.70710678118654752f));
                    *(unsigned short*)(smem + HL + m * 512 + ((hc * 2) ^ ((m & 7) << 4))) = f2bf(g);
                }
        __syncthreads();

        // ---- GEMM2: Y[32x128] = H @ W2; wave wv owns d-cols [wv*32, +32) ----
        f32x4 acc2[2][2];
#pragma unroll
        for (int mt = 0; mt < 2; mt++)
#pragma unroll
            for (int nt = 0; nt < 2; nt++) acc2[mt][nt] = zero;
#pragma unroll
        for (int ks = 0; ks < 8; ks++) {
            int kb = ks * 64 + lhi * 16;
            s16x8 a0 = *(const s16x8*)(smem + HL + llo * 512        + (kb ^ ((llo & 7) << 4)));
            s16x8 a1 = *(const s16x8*)(smem + HL + (llo + 16) * 512 + (kb ^ ((llo & 7) << 4)));
#pragma unroll
            for (int nt = 0; nt < 2; nt++) {
                int d = wv * 32 + nt * 16 + llo;
                s16x8 b = *(const s16x8*)((const char*)w2c +
                          ((((size_t)(e * 8 + ks) << 7) + d) * 4 + lhi) * 16);
                acc2[0][nt] = __builtin_amdgcn_mfma_f32_16x16x32_bf16(a0, b, acc2[0][nt], 0, 0, 0);
                acc2[1][nt] = __builtin_amdgcn_mfma_f32_16x16x32_bf16(a1, b, acc2[1][nt], 0, 0, 0);
            }
        }

        // ---- epilogue: y = gw * (acc + b2) -> ybuf (bf16) ----
#pragma unroll
        for (int mt = 0; mt < 2; mt++)
#pragma unroll
            for (int r = 0; r < 4; r++) {
                int m = mt * 16 + lhi * 4 + r;
                if (m < rows) {
                    int p = plist[e * CAP + r0 + m];
                    float gw = gwbuf[p];
#pragma unroll
                    for (int nt = 0; nt < 2; nt++) {
                        int d = wv * 32 + nt * 16 + llo;
                        ybuf[(size_t)p * D + d] = f2bf(gw * (acc2[mt][nt][r] + b2[e * D + d]));
                    }
                }
            }
    }
}

// ---------------- BatchNorm ----------------
__global__ __launch_bounds__(256) void k_bnpart(const float* __restrict__ nf,
                                                const unsigned short* __restrict__ ybuf,
                                                double* __restrict__ part) {
    int blk = blockIdx.x;
    int col = threadIdx.x & 127;
    int half = threadIdx.x >> 7;
    int r0 = blk * BN_ROWS;
    int r1 = min(r0 + BN_ROWS, N_NODES);
    double s = 0.0, ss = 0.0;
    for (int r = r0 + half; r < r1; r += 2) {
        float v32 = nf[(size_t)r * D + col]
                  + bf2f(ybuf[(size_t)(2 * r) * D + col])
                  + bf2f(ybuf[(size_t)(2 * r + 1) * D + col]);
        double v = (double)v32;
        s += v; ss += v * v;
    }
    __shared__ double sh[2][256];
    sh[0][threadIdx.x] = s; sh[1][threadIdx.x] = ss;
    __syncthreads();
    if (threadIdx.x < 128) {
        part[(size_t)blk * 256 + col]       = sh[0][col] + sh[0][col + 128];
        part[(size_t)blk * 256 + 128 + col] = sh[1][col] + sh[1][col + 128];
    }
}

__global__ void k_bnstats(const double* __restrict__ part,
                          const float* __restrict__ gamma,
                          float* __restrict__ stats) {
    int col = threadIdx.x;   // 128 threads
    double s = 0.0, ss = 0.0;
    for (int b = 0; b < BN_NBLK; b++) {
        s  += part[(size_t)b * 256 + col];
        ss += part[(size_t)b * 256 + 128 + col];
    }
    double mean = s / (double)N_NODES;
    double var = ss / (double)N_NODES - mean * mean;
    stats[col] = (float)mean;
    stats[128 + col] = gamma[col] * (float)(1.0 / sqrt(var + 1e-5));
}

__global__ __launch_bounds__(256) void k_bnapply(const unsigned short* __restrict__ ybuf,
                                                 const float* __restrict__ stats,
                                                 const float* __restrict__ beta,
                                                 float* __restrict__ out) {
    int i = blockIdx.x * blockDim.x + threadIdx.x;   // float4 index
    if (i >= N_NODES * (D / 4)) return;
    int t = i >> 5;
    int q = i & 31;
    int c0 = q * 4;
    float4 v  = ((float4*)out)[i];
    short4 y0v = *(const short4*)(ybuf + (size_t)(2 * t) * D + c0);
    short4 y1v = *(const short4*)(ybuf + (size_t)(2 * t + 1) * D + c0);
    float4 r;
    r.x = (v.x + bf2f((unsigned short)y0v.x) + bf2f((unsigned short)y1v.x) - stats[c0 + 0]) * stats[128 + c0 + 0] + beta[c0 + 0];
    r.y = (v.y + bf2f((unsigned short)y0v.y) + bf2f((unsigned short)y1v.y) - stats[c0 + 1]) * stats[128 + c0 + 1] + beta[c0 + 1];
    r.z = (v.z + bf2f((unsigned short)y0v.z) + bf2f((unsigned short)y1v.z) - stats[c0 + 2]) * stats[128 + c0 + 2] + beta[c0 + 2];
    r.w = (v.w + bf2f((unsigned short)y0v.w) + bf2f((unsigned short)y1v.w) - stats[c0 + 3]) * stats[128 + c0 + 3] + beta[c0 + 3];
    ((float4*)out)[i] = r;
}

// ---------------- launch ----------------
extern "C" void kernel_launch(void* const* d_in, const int* in_sizes, int n_in,
                              void* d_out, int out_size, void* d_ws, size_t ws_size,
                              hipStream_t stream) {
    const float* feats   = (const float*)d_in[0];
    const int*   esrc    = (const int*)d_in[1];
    const int*   edst    = (const int*)d_in[2];
    const float* W_conv  = (const float*)d_in[3];
    const float* b_conv  = (const float*)d_in[4];
    const float* gate_W  = (const float*)d_in[5];
    const float* gate_b  = (const float*)d_in[6];
    const float* W1      = (const float*)d_in[7];
    const float* b1      = (const float*)d_in[8];
    const float* W2      = (const float*)d_in[9];
    const float* b2      = (const float*)d_in[10];
    const float* bn_g    = (const float*)d_in[11];
    const float* bn_b    = (const float*)d_in[12];
    float* out = (float*)d_out;   // doubles as new_feats storage

    char* ws = (char*)d_ws;
    size_t off = 0;
    auto rup = [](size_t x) { return (x + 255) & ~(size_t)255; };
    int*    deg    = (int*)   (ws + off); off += rup((size_t)N_NODES * 4);
    int*    cursor = (int*)   (ws + off); off += rup((size_t)N_NODES * 4);
    int*    cnt    = (int*)   (ws + off); off += 256;
    size_t zero_bytes = off;                 // deg + cursor + cnt (~400 KB)
    float*  invs   = (float*) (ws + off); off += rup((size_t)N_NODES * 4);
    int*    rowptr = (int*)   (ws + off); off += rup((size_t)(N_NODES + 1) * 4);
    int*    csr    = (int*)   (ws + off); off += rup((size_t)N_EDGES * 4);
    float*  gwbuf  = (float*) (ws + off); off += rup((size_t)NPAIR * 4);
    int*    topi   = (int*)   (ws + off); off += rup((size_t)NPAIR * 4);
    int*    plist  = (int*)   (ws + off); off += rup((size_t)NE * CAP * 4);
    double* part   = (double*)(ws + off); off += rup((size_t)BN_NBLK * 256 * 8);
    float*  stats  = (float*) (ws + off); off += 1024;
    unsigned short* w1c = (unsigned short*)(ws + off); off += rup((size_t)NE * D * H * 2); // 4 MB
    unsigned short* w2c = (unsigned short*)(ws + off); off += rup((size_t)NE * D * H * 2); // 4 MB
    unsigned short* ybuf = (unsigned short*)(ws + off); off += rup((size_t)NPAIR * D * 2); // 25.6 MB
    float*  agg    = (float*)ybuf;   // lifetime-disjoint alias (agg dead before k_moe writes ybuf)
    (void)ws_size; (void)in_sizes; (void)n_in; (void)out_size;

    hipMemsetAsync(d_ws, 0, zero_bytes, stream);

    k_wconv<<<2 * NE * 4 * 256 * 4 / 256, 256, 0, stream>>>(W1, W2, w1c, w2c);
    k_deg<<<(N_EDGES + 255) / 256, 256, 0, stream>>>(edst, deg);
    k_invsqrt<<<(N_NODES + 255) / 256, 256, 0, stream>>>(deg, invs);
    k_scan<<<1, 1024, 0, stream>>>(deg, rowptr);
    k_scatter<<<(N_EDGES + 255) / 256, 256, 0, stream>>>(esrc, edst, rowptr, cursor, csr);
    k_gather<<<(N_NODES + 3) / 4, 256, 0, stream>>>(feats, rowptr, csr, invs, agg);
    k_conv<<<(N_NODES + TILE_R - 1) / TILE_R, 256, 0, stream>>>(agg, W_conv, b_conv, out);
    k_gate<<<N_NODES / 16, 256, 0, stream>>>(out, gate_W, gate_b, gwbuf, topi);
    k_disp<<<(NPAIR + 1023) / 1024, 1024, 0, stream>>>(topi, cnt, plist);
    k_moe<<<NE * BQ, 256, 0, stream>>>(out, cnt, plist, w1c, b1, w2c, b2, gwbuf, ybuf);
    k_bnpart<<<BN_NBLK, 256, 0, stream>>>(out, ybuf, part);
    k_bnstats<<<1, 128, 0, stream>>>(part, bn_g, stats);
    k_bnapply<<<(N_NODES * (D / 4) + 255) / 256, 256, 0, stream>>>(ybuf, stats, bn_b, out);
}

// Round 10
// 602.321 us; speedup vs baseline: 1.0979x; 1.0979x over previous
//
#include <hip/hip_runtime.h>
#include <math.h>

#define N_NODES 50000
#define N_EDGES 500000
#define D 128
#define H 256
#define NE 64
#define TOPK 2
#define NPAIR (N_NODES * TOPK)
#define CAP 3126               // 2 * ceil(100000/64)
#define TILE_R 32
#define BQ 4                   // blocks per expert in k_moe
#define BN_NBLK 128
#define BN_ROWS ((N_NODES + BN_NBLK - 1) / BN_NBLK) // 391

typedef __attribute__((ext_vector_type(8))) short s16x8;
typedef __attribute__((ext_vector_type(4))) float f32x4;

__device__ __forceinline__ unsigned short f2bf(float f) {
    unsigned u = __float_as_uint(f);
    unsigned r = (u + 0x7fffu + ((u >> 16) & 1u)) >> 16;
    return (unsigned short)r;
}
__device__ __forceinline__ float bf2f(unsigned short u) {
    return __uint_as_float(((unsigned)u) << 16);
}

// Compensated f32: TwoProd (mul + fma residual) + branch-free TwoSum.
#define DOT2(s, c, xx, ww) {                      \
    float p_ = (xx) * (ww);                       \
    float e1_ = fmaf((xx), (ww), -p_);            \
    float t_ = (s) + p_;                          \
    float z_ = t_ - (s);                          \
    float e2_ = ((s) - (t_ - z_)) + (p_ - z_);    \
    (s) = t_;                                     \
    (c) += e1_ + e2_; }

#define TSUM(s, c, pp) {                          \
    float p_ = (pp);                              \
    float t_ = (s) + p_;                          \
    float z_ = t_ - (s);                          \
    float e2_ = ((s) - (t_ - z_)) + (p_ - z_);    \
    (s) = t_;                                     \
    (c) += e2_; }

// ---------------- degree count ----------------
__global__ void k_deg(const int* __restrict__ dst, int* __restrict__ deg) {
    int i = blockIdx.x * blockDim.x + threadIdx.x;
    if (i < N_EDGES) atomicAdd(&deg[dst[i]], 1);
}

__global__ void k_invsqrt(const int* __restrict__ deg, float* __restrict__ invs) {
    int i = blockIdx.x * blockDim.x + threadIdx.x;
    if (i < N_NODES) {
        double d = (double)deg[i];
        if (d < 1.0) d = 1.0;
        invs[i] = (float)(1.0 / sqrt(d));
    }
}

// ---------------- exclusive scan of deg -> rowptr ----------------
__global__ __launch_bounds__(1024) void k_scan(const int* __restrict__ deg,
                                               int* __restrict__ rowptr) {
    __shared__ int sh[1024];
    int t = threadIdx.x;
    const int chunk = (N_NODES + 1023) / 1024;   // 49
    int lo = t * chunk;
    int hi = min(lo + chunk, N_NODES);
    int s = 0;
    for (int i = lo; i < hi; i++) s += deg[i];
    sh[t] = s;
    __syncthreads();
    for (int off = 1; off < 1024; off <<= 1) {
        int v = (t >= off) ? sh[t - off] : 0;
        __syncthreads();
        sh[t] += v;
        __syncthreads();
    }
    int run = (t == 0) ? 0 : sh[t - 1];
    for (int i = lo; i < hi; i++) { rowptr[i] = run; run += deg[i]; }
    if (t == 1023) rowptr[N_NODES] = run;
}

// ---------------- scatter edges into CSR ----------------
__global__ void k_scatter(const int* __restrict__ src, const int* __restrict__ dst,
                          const int* __restrict__ rowptr, int* __restrict__ cursor,
                          int* __restrict__ csr) {
    int e = blockIdx.x * blockDim.x + threadIdx.x;
    if (e >= N_EDGES) return;
    int d = dst[e];
    int pos = atomicAdd(&cursor[d], 1);
    csr[rowptr[d] + pos] = src[e];
}

// ---------------- per-node gather (compensated f32, order-independent ~1e-12) ----
__global__ __launch_bounds__(256) void k_gather(const float* __restrict__ feats,
                                                const int* __restrict__ rowptr,
                                                const int* __restrict__ csr,
                                                const float* __restrict__ invs,
                                                float* __restrict__ agg) {
    int node = blockIdx.x * 4 + (threadIdx.x >> 6);
    if (node >= N_NODES) return;
    int lane = threadIdx.x & 63;
    int beg = rowptr[node], end = rowptr[node + 1];
    float wd = invs[node];
    float sx = 0.f, cx = 0.f, sy = 0.f, cy = 0.f;
    for (int i = beg; i < end; i++) {
        int s = csr[i];
        float nrm = invs[s] * wd;
        float2 f = ((const float2*)(feats + (size_t)s * D))[lane];
        DOT2(sx, cx, nrm, f.x);
        DOT2(sy, cy, nrm, f.y);
    }
    ((float2*)(agg + (size_t)node * D))[lane] = make_float2(sx + cx, sy + cy);
}

// ---------------- conv GEMM: new_feats = agg @ W_conv + b_conv (fp32, untouched) ----
__global__ __launch_bounds__(256) void k_conv(const float* __restrict__ agg,
                                              const float* __restrict__ W,
                                              const float* __restrict__ bias,
                                              float* __restrict__ out) {
    __shared__ float Wl[D * D];        // 64 KB
    __shared__ float xl[TILE_R * D];   // 16 KB
    int r0 = blockIdx.x * TILE_R;
    int rows = min(TILE_R, N_NODES - r0);
    for (int i = threadIdx.x; i < D * D / 4; i += 256)
        ((float4*)Wl)[i] = ((const float4*)W)[i];
    for (int i = threadIdx.x; i < rows * 32; i += 256) {
        int r = i >> 5, q = i & 31;
        ((float4*)(xl + r * D))[q] = ((const float4*)(agg + (size_t)(r0 + r) * D))[q];
    }
    __syncthreads();
    int c = threadIdx.x & 127;
    int half = threadIdx.x >> 7;
    float acc[16];
#pragma unroll
    for (int j = 0; j < 16; j++) acc[j] = 0.f;
    for (int k = 0; k < D; k++) {
        float w = Wl[k * D + c];
#pragma unroll
        for (int j = 0; j < 16; j++) acc[j] += xl[(half + j * 2) * D + k] * w;
    }
    float b = bias[c];
#pragma unroll
    for (int j = 0; j < 16; j++) {
        int r = half + j * 2;
        if (r < rows) out[(size_t)(r0 + r) * D + c] = acc[j] + b;
    }
}

// ---------------- gate v5: comp-f32 scores, (v,r,idx) top-2, no atomics ----------------
__global__ __launch_bounds__(256) void k_gate(const float* __restrict__ nf,
                                              const float* __restrict__ gW,
                                              const float* __restrict__ gb,
                                              float* __restrict__ gwout,
                                              int* __restrict__ topi) {
    __shared__ float Wl[D * NE];       // 32 KB, layout [k][e]
    __shared__ float xsh[16 * D];      // 8 KB
    for (int i = threadIdx.x; i < D * NE / 4; i += 256)
        ((float4*)Wl)[i] = ((const float4*)gW)[i];
    int t_base = blockIdx.x * 16;
    for (int i = threadIdx.x; i < 16 * 32; i += 256) {
        int r = i >> 5, q = i & 31;
        ((float4*)(xsh + r * D))[q] =
            ((const float4*)(nf + (size_t)(t_base + r) * D))[q];
    }
    __syncthreads();

    int wave = threadIdx.x >> 6;
    int lane = threadIdx.x & 63;      // lane = expert
    int t0 = t_base + wave * 4;
    const float* xw = xsh + wave * 4 * D;

    float s0 = 0.f, c0 = 0.f, s1 = 0.f, c1 = 0.f;
    float s2 = 0.f, c2 = 0.f, s3 = 0.f, c3 = 0.f;
    for (int k4 = 0; k4 < D; k4 += 4) {
        float x0[4], x1[4], x2[4], x3[4];
        *(float4*)x0 = *(const float4*)(xw + k4);
        *(float4*)x1 = *(const float4*)(xw + D + k4);
        *(float4*)x2 = *(const float4*)(xw + 2 * D + k4);
        *(float4*)x3 = *(const float4*)(xw + 3 * D + k4);
#pragma unroll
        for (int u = 0; u < 4; u++) {
            float w = Wl[(k4 + u) * NE + lane];
            DOT2(s0, c0, x0[u], w);
            DOT2(s1, c1, x1[u], w);
            DOT2(s2, c2, x2[u], w);
            DOT2(s3, c3, x3[u], w);
        }
    }
    float gbf = gb[lane];
    TSUM(s0, c0, gbf);
    TSUM(s1, c1, gbf);
    TSUM(s2, c2, gbf);
    TSUM(s3, c3, gbf);
    float v0 = s0 + c0, r0 = (s0 - v0) + c0;
    float v1 = s1 + c1, r1 = (s1 - v1) + c1;
    float v2 = s2 + c2, r2 = (s2 - v2) + c2;
    float v3 = s3 + c3, r3 = (s3 - v3) + c3;

#pragma unroll
    for (int j = 0; j < 4; j++) {
        float vv = (j == 0) ? v0 : (j == 1) ? v1 : (j == 2) ? v2 : v3;
        float rr = (j == 0) ? r0 : (j == 1) ? r1 : (j == 2) ? r2 : r3;
        int t = t0 + j;

        float a1v = vv, a1r = rr; int i1 = lane;
#pragma unroll
        for (int off = 32; off; off >>= 1) {
            float ov = __shfl_xor(a1v, off);
            float orr = __shfl_xor(a1r, off);
            int   oi = __shfl_xor(i1, off);
            bool gt = (ov > a1v) || (ov == a1v && (orr > a1r || (orr == a1r && oi < i1)));
            if (gt) { a1v = ov; a1r = orr; i1 = oi; }
        }
        bool ex = (lane == i1);
        float a2v = ex ? -INFINITY : vv;
        float a2r = ex ? 0.f : rr;
        int i2 = lane;
#pragma unroll
        for (int off = 32; off; off >>= 1) {
            float ov = __shfl_xor(a2v, off);
            float orr = __shfl_xor(a2r, off);
            int   oi = __shfl_xor(i2, off);
            bool gt = (ov > a2v) || (ov == a2v && (orr > a2r || (orr == a2r && oi < i2)));
            if (gt) { a2v = ov; a2r = orr; i2 = oi; }
        }

        if (lane == 0) {
            float dd = (a2v - a1v) + (a2r - a1r);
            float e2 = expf(dd);
            float g0 = 1.0f / (1.0f + e2);
            gwout[2 * t] = g0;
            gwout[2 * t + 1] = e2 * g0;
            topi[2 * t] = i1;
            topi[2 * t + 1] = i2;
        }
    }
}

// ---------------- dispatch: parallel two-level counting scatter ----------------
__global__ __launch_bounds__(1024) void k_disp(const int* __restrict__ topi,
                                               int* __restrict__ cnt,
                                               int* __restrict__ plist) {
    __shared__ int lcnt[NE];
    __shared__ int lbase[NE];
    int tid = threadIdx.x;
    if (tid < NE) lcnt[tid] = 0;
    __syncthreads();
    int p = blockIdx.x * 1024 + tid;
    int e = 0, lr = 0;
    bool act = (p < NPAIR);
    if (act) {
        e = topi[p];
        lr = atomicAdd(&lcnt[e], 1);
    }
    __syncthreads();
    if (tid < NE) {
        int n = lcnt[tid];
        lbase[tid] = n ? atomicAdd(&cnt[tid], n) : 0;
    }
    __syncthreads();
    if (act) {
        int slot = lbase[e] + lr;
        if (slot < CAP) plist[e * CAP + slot] = p;
    }
}

// ---------------- weight convert: f32 -> bf16 fragments, PRE-SWIZZLED --------------
// 16B unit u1 = (ks*256+h)*4+lhi stored at byte (u1*16)^((h&7)<<4) within expert's 64KB
// 16B unit u2 = (ks*128+d)*4+lhi stored at byte (u2*16)^((d&7)<<4)
__global__ __launch_bounds__(256) void k_wconv(const float* __restrict__ W1,
                                               const float* __restrict__ W2,
                                               unsigned short* __restrict__ w1c,
                                               unsigned short* __restrict__ w2c) {
    int gid = blockIdx.x * 256 + threadIdx.x;
    const int NW1 = NE * 4 * 256 * 4;            // 262144
    if (gid < NW1) {
        int lhi = gid & 3, h = (gid >> 2) & 255, ks = (gid >> 10) & 3, e = gid >> 12;
        int u = gid & 4095;                       // (ks*256+h)*4+lhi
        int d0 = ks * 32 + lhi * 8;
        unsigned short v[8] __attribute__((aligned(16)));
#pragma unroll
        for (int j = 0; j < 8; j++)
            v[j] = f2bf(W1[((size_t)e * D + d0 + j) * H + h]);
        *(int4*)((char*)w1c + (size_t)e * 65536 + ((u * 16) ^ ((h & 7) << 4))) = *(int4*)v;
    } else {
        int g = gid - NW1;
        int lhi = g & 3, d = (g >> 2) & 127, ks = (g >> 9) & 7, e = g >> 12;
        int u = g & 4095;                         // (ks*128+d)*4+lhi
        int h0 = ks * 32 + lhi * 8;
        unsigned short v[8] __attribute__((aligned(16)));
#pragma unroll
        for (int j = 0; j < 8; j++)
            v[j] = f2bf(W2[((size_t)e * H + h0 + j) * D + d]);
        *(int4*)((char*)w2c + (size_t)e * 65536 + ((u * 16) ^ ((d & 7) << 4))) = *(int4*)v;
    }
}

// ---------------- MoE FFN v4: 8 waves, W1+W2 resident in LDS (copied, pre-swizzled) --
// LDS: W1L 64KB | W2L 64KB | XA [32][128]bf16 8KB | HL [32][256]bf16 16KB = 152KB
__global__ __launch_bounds__(512, 1) void k_moe(const float* __restrict__ nf,
                                                const int* __restrict__ cnt,
                                                const int* __restrict__ plist,
                                                const unsigned short* __restrict__ w1c,
                                                const float* __restrict__ b1,
                                                const unsigned short* __restrict__ w2c,
                                                const float* __restrict__ b2,
                                                const float* __restrict__ gwbuf,
                                                unsigned short* __restrict__ ybuf) {
    __shared__ __align__(16) char smem[155648];
    const int W1L = 0, W2L = 65536, XA = 131072, HL = 139264;
    int e = blockIdx.x >> 2;
    int q = blockIdx.x & 3;
    int n = min(cnt[e], CAP);
    int ntile = (n + TILE_R - 1) / TILE_R;
    if (q >= ntile) return;
    int tid = threadIdx.x;

    // ---- stage W1+W2 fragments: pure 16B copy (coalesced read, conflict-free write) ----
    {
        const int4* s1 = (const int4*)((const char*)w1c + (size_t)e * 65536);
        const int4* s2 = (const int4*)((const char*)w2c + (size_t)e * 65536);
#pragma unroll
        for (int i = 0; i < 8; i++) {
            ((int4*)(smem + W1L))[tid + i * 512] = s1[tid + i * 512];
            ((int4*)(smem + W2L))[tid + i * 512] = s2[tid + i * 512];
        }
    }

    int wv = tid >> 6, lane = tid & 63;
    int lhi = lane >> 4, llo = lane & 15;
    f32x4 zero = {0.f, 0.f, 0.f, 0.f};

    for (int rt = q; rt < ntile; rt += BQ) {
        int r0 = rt * TILE_R;
        int rows = min(TILE_R, n - r0);
        __syncthreads();   // W staged; XA/HL safe to overwrite

        // ---- gather 32 x-rows -> XA (bf16, swizzled); 512 threads, 16B/thread ----
        {
            int r = tid >> 4, s = tid & 15;
            float vals[8];
            if (r < rows) {
                int p = plist[e * CAP + r0 + r];
                const float4* xr = (const float4*)(nf + (size_t)(p >> 1) * D + s * 8);
                *(float4*)(vals + 0) = xr[0];
                *(float4*)(vals + 4) = xr[1];
            } else {
#pragma unroll
                for (int k = 0; k < 8; k++) vals[k] = 0.f;
            }
            unsigned short hb[8] __attribute__((aligned(16)));
#pragma unroll
            for (int k = 0; k < 8; k++) hb[k] = f2bf(vals[k]);
            *(int4*)(smem + XA + r * 256 + ((s * 16) ^ ((r & 7) << 4))) = *(int4*)hb;
        }
        __syncthreads();

        // ---- GEMM1: H[32x256] = X @ W1; wave wv owns h-cols [wv*32, +32) ----
        f32x4 acc1[2][2];
#pragma unroll
        for (int mt = 0; mt < 2; mt++)
#pragma unroll
            for (int nt = 0; nt < 2; nt++) acc1[mt][nt] = zero;
#pragma unroll
        for (int ks = 0; ks < 4; ks++) {
            int kb = ks * 64 + lhi * 16;
            s16x8 a0 = *(const s16x8*)(smem + XA + llo * 256        + (kb ^ ((llo & 7) << 4)));
            s16x8 a1 = *(const s16x8*)(smem + XA + (llo + 16) * 256 + (kb ^ ((llo & 7) << 4)));
#pragma unroll
            for (int nt = 0; nt < 2; nt++) {
                int h = wv * 32 + nt * 16 + llo;
                int u = (ks * 256 + h) * 4 + lhi;
                s16x8 b = *(const s16x8*)(smem + W1L + ((u * 16) ^ ((h & 7) << 4)));
                acc1[0][nt] = __builtin_amdgcn_mfma_f32_16x16x32_bf16(a0, b, acc1[0][nt], 0, 0, 0);
                acc1[1][nt] = __builtin_amdgcn_mfma_f32_16x16x32_bf16(a1, b, acc1[1][nt], 0, 0, 0);
            }
        }

        // ---- gelu -> HL (bf16, swizzled) ----
#pragma unroll
        for (int mt = 0; mt < 2; mt++)
#pragma unroll
            for (int nt = 0; nt < 2; nt++)
#pragma unroll
                for (int r = 0; r < 4; r++) {
                    int m = mt * 16 + lhi * 4 + r;
                    int hc = wv * 32 + nt * 16 + llo;
                    float hv = acc1[mt][nt][r] + b1[e * H + hc];
                    float g = 0.5f * hv * (1.0f + erff(hv * 0.70710678118654752f));
                    *(unsigned short*)(smem + HL + m * 512 + ((hc * 2) ^ ((m & 7) << 4))) = f2bf(g);
                }
        __syncthreads();

        // ---- GEMM2: Y[32x128] = H @ W2; wave wv owns d-cols [wv*16, +16) ----
        f32x4 acc2[2];
        acc2[0] = zero; acc2[1] = zero;
#pragma unroll
        for (int ks = 0; ks < 8; ks++) {
            int kb = ks * 64 + lhi * 16;
            s16x8 a0 = *(const s16x8*)(smem + HL + llo * 512        + (kb ^ ((llo & 7) << 4)));
            s16x8 a1 = *(const s16x8*)(smem + HL + (llo + 16) * 512 + (kb ^ ((llo & 7) << 4)));
            int d = wv * 16 + llo;
            int u = (ks * 128 + d) * 4 + lhi;
            s16x8 b = *(const s16x8*)(smem + W2L + ((u * 16) ^ ((d & 7) << 4)));
            acc2[0] = __builtin_amdgcn_mfma_f32_16x16x32_bf16(a0, b, acc2[0], 0, 0, 0);
            acc2[1] = __builtin_amdgcn_mfma_f32_16x16x32_bf16(a1, b, acc2[1], 0, 0, 0);
        }

        // ---- epilogue: y = gw * (acc + b2) -> ybuf (bf16) ----
        int d = wv * 16 + llo;
        float bb = b2[e * D + d];
#pragma unroll
        for (int mt = 0; mt < 2; mt++)
#pragma unroll
            for (int r = 0; r < 4; r++) {
                int m = mt * 16 + lhi * 4 + r;
                if (m < rows) {
                    int p = plist[e * CAP + r0 + m];
                    ybuf[(size_t)p * D + d] = f2bf(gwbuf[p] * (acc2[mt][r] + bb));
                }
            }
    }
}

// ---------------- BatchNorm ----------------
__global__ __launch_bounds__(256) void k_bnpart(const float* __restrict__ nf,
                                                const unsigned short* __restrict__ ybuf,
                                                double* __restrict__ part) {
    int blk = blockIdx.x;
    int col = threadIdx.x & 127;
    int half = threadIdx.x >> 7;
    int r0 = blk * BN_ROWS;
    int r1 = min(r0 + BN_ROWS, N_NODES);
    double s = 0.0, ss = 0.0;
    for (int r = r0 + half; r < r1; r += 2) {
        float v32 = nf[(size_t)r * D + col]
                  + bf2f(ybuf[(size_t)(2 * r) * D + col])
                  + bf2f(ybuf[(size_t)(2 * r + 1) * D + col]);
        double v = (double)v32;
        s += v; ss += v * v;
    }
    __shared__ double sh[2][256];
    sh[0][threadIdx.x] = s; sh[1][threadIdx.x] = ss;
    __syncthreads();
    if (threadIdx.x < 128) {
        part[(size_t)blk * 256 + col]       = sh[0][col] + sh[0][col + 128];
        part[(size_t)blk * 256 + 128 + col] = sh[1][col] + sh[1][col + 128];
    }
}

__global__ void k_bnstats(const double* __restrict__ part,
                          const float* __restrict__ gamma,
                          float* __restrict__ stats) {
    int col = threadIdx.x;   // 128 threads
    double s = 0.0, ss = 0.0;
    for (int b = 0; b < BN_NBLK; b++) {
        s  += part[(size_t)b * 256 + col];
        ss += part[(size_t)b * 256 + 128 + col];
    }
    double mean = s / (double)N_NODES;
    double var = ss / (double)N_NODES - mean * mean;
    stats[col] = (float)mean;
    stats[128 + col] = gamma[col] * (float)(1.0 / sqrt(var + 1e-5));
}

__global__ __launch_bounds__(256) void k_bnapply(const unsigned short* __restrict__ ybuf,
                                                 const float* __restrict__ stats,
                                                 const float* __restrict__ beta,
                                                 float* __restrict__ out) {
    int i = blockIdx.x * blockDim.x + threadIdx.x;   // float4 index
    if (i >= N_NODES * (D / 4)) return;
    int t = i >> 5;
    int q = i & 31;
    int c0 = q * 4;
    float4 v  = ((float4*)out)[i];
    short4 y0v = *(const short4*)(ybuf + (size_t)(2 * t) * D + c0);
    short4 y1v = *(const short4*)(ybuf + (size_t)(2 * t + 1) * D + c0);
    float4 r;
    r.x = (v.x + bf2f((unsigned short)y0v.x) + bf2f((unsigned short)y1v.x) - stats[c0 + 0]) * stats[128 + c0 + 0] + beta[c0 + 0];
    r.y = (v.y + bf2f((unsigned short)y0v.y) + bf2f((unsigned short)y1v.y) - stats[c0 + 1]) * stats[128 + c0 + 1] + beta[c0 + 1];
    r.z = (v.z + bf2f((unsigned short)y0v.z) + bf2f((unsigned short)y1v.z) - stats[c0 + 2]) * stats[128 + c0 + 2] + beta[c0 + 2];
    r.w = (v.w + bf2f((unsigned short)y0v.w) + bf2f((unsigned short)y1v.w) - stats[c0 + 3]) * stats[128 + c0 + 3] + beta[c0 + 3];
    ((float4*)out)[i] = r;
}

// ---------------- launch ----------------
extern "C" void kernel_launch(void* const* d_in, const int* in_sizes, int n_in,
                              void* d_out, int out_size, void* d_ws, size_t ws_size,
                              hipStream_t stream) {
    const float* feats   = (const float*)d_in[0];
    const int*   esrc    = (const int*)d_in[1];
    const int*   edst    = (const int*)d_in[2];
    const float* W_conv  = (const float*)d_in[3];
    const float* b_conv  = (const float*)d_in[4];
    const float* gate_W  = (const float*)d_in[5];
    const float* gate_b  = (const float*)d_in[6];
    const float* W1      = (const float*)d_in[7];
    const float* b1      = (const float*)d_in[8];
    const float* W2      = (const float*)d_in[9];
    const float* b2      = (const float*)d_in[10];
    const float* bn_g    = (const float*)d_in[11];
    const float* bn_b    = (const float*)d_in[12];
    float* out = (float*)d_out;   // doubles as new_feats storage

    char* ws = (char*)d_ws;
    size_t off = 0;
    auto rup = [](size_t x) { return (x + 255) & ~(size_t)255; };
    int*    deg    = (int*)   (ws + off); off += rup((size_t)N_NODES * 4);
    int*    cursor = (int*)   (ws + off); off += rup((size_t)N_NODES * 4);
    int*    cnt    = (int*)   (ws + off); off += 256;
    size_t zero_bytes = off;                 // deg + cursor + cnt (~400 KB)
    float*  invs   = (float*) (ws + off); off += rup((size_t)N_NODES * 4);
    int*    rowptr = (int*)   (ws + off); off += rup((size_t)(N_NODES + 1) * 4);
    int*    csr    = (int*)   (ws + off); off += rup((size_t)N_EDGES * 4);
    float*  gwbuf  = (float*) (ws + off); off += rup((size_t)NPAIR * 4);
    int*    topi   = (int*)   (ws + off); off += rup((size_t)NPAIR * 4);
    int*    plist  = (int*)   (ws + off); off += rup((size_t)NE * CAP * 4);
    double* part   = (double*)(ws + off); off += rup((size_t)BN_NBLK * 256 * 8);
    float*  stats  = (float*) (ws + off); off += 1024;
    unsigned short* w1c = (unsigned short*)(ws + off); off += rup((size_t)NE * D * H * 2); // 4 MB
    unsigned short* w2c = (unsigned short*)(ws + off); off += rup((size_t)NE * D * H * 2); // 4 MB
    unsigned short* ybuf = (unsigned short*)(ws + off); off += rup((size_t)NPAIR * D * 2); // 25.6 MB
    float*  agg    = (float*)ybuf;   // lifetime-disjoint alias (agg dead before k_moe writes ybuf)
    (void)ws_size; (void)in_sizes; (void)n_in; (void)out_size;

    hipMemsetAsync(d_ws, 0, zero_bytes, stream);

    k_wconv<<<2 * NE * 4 * 256 * 4 / 256, 256, 0, stream>>>(W1, W2, w1c, w2c);
    k_deg<<<(N_EDGES + 255) / 256, 256, 0, stream>>>(edst, deg);
    k_invsqrt<<<(N_NODES + 255) / 256, 256, 0, stream>>>(deg, invs);
    k_scan<<<1, 1024, 0, stream>>>(deg, rowptr);
    k_scatter<<<(N_EDGES + 255) / 256, 256, 0, stream>>>(esrc, edst, rowptr, cursor, csr);
    k_gather<<<(N_NODES + 3) / 4, 256, 0, stream>>>(feats, rowptr, csr, invs, agg);
    k_conv<<<(N_NODES + TILE_R - 1) / TILE_R, 256, 0, stream>>>(agg, W_conv, b_conv, out);
    k_gate<<<N_NODES / 16, 256, 0, stream>>>(out, gate_W, gate_b, gwbuf, topi);
    k_disp<<<(NPAIR + 1023) / 1024, 1024, 0, stream>>>(topi, cnt, plist);
    k_moe<<<NE * BQ, 512, 0, stream>>>(out, cnt, plist, w1c, b1, w2c, b2, gwbuf, ybuf);
    k_bnpart<<<BN_NBLK, 256, 0, stream>>>(out, ybuf, part);
    k_bnstats<<<1, 128, 0, stream>>>(part, bn_g, stats);
    k_bnapply<<<(N_NODES * (D / 4) + 255) / 256, 256, 0, stream>>>(ybuf, stats, bn_b, out);
}